// Round 1
// baseline (69.446 us; speedup 1.0000x reference)
//
#include <hip/hip_runtime.h>

// RecPolicy: per-row, 7-step bidirectional GRU (H=2) + obs linear + scalar head.
// x: (B,18) f32 = [obs(4), j(7), jd(7)]
// out: (B,7) f32
//
// Entirely row-parallel: 1 thread = 1 row. All inner loops fully unrolled.

#define NROWS 2097152

__device__ __forceinline__ float fexp(float x) {
    // e^x = 2^(x*log2(e)) -> single v_exp_f32
    return __builtin_amdgcn_exp2f(x * 1.4426950408889634f);
}
__device__ __forceinline__ float frcp(float x) {
    return __builtin_amdgcn_rcpf(x);
}
__device__ __forceinline__ float fsigmoid(float x) {
    // 1/(1+e^-x); e^-x -> inf for very negative x, rcp(inf)=0 -> sigmoid=0. OK.
    return frcp(1.0f + fexp(-x));
}
__device__ __forceinline__ float ftanh(float x) {
    // tanh(x) = 1 - 2/(e^{2x}+1); e^{2x}->inf => 1, ->0 => -1. OK at extremes.
    return 1.0f - 2.0f * frcp(1.0f + __builtin_amdgcn_exp2f(x * 2.8853900817779268f));
}

// One GRU cell, H=2, input dim 2, fully scalar-unrolled.
// wih/whh are (6,2) row-major, b* are (6,). Updates h0,h1 in place.
__device__ __forceinline__ void gru_cell(
    float x0, float x1, float& h0, float& h1,
    const float wih[12], const float whh[12],
    const float bih[6], const float bhh[6])
{
    // r,z gates: gi+gh fused
    float g0 = (bih[0] + bhh[0]) + wih[0]*x0 + wih[1]*x1 + whh[0]*h0 + whh[1]*h1;
    float g1 = (bih[2] + bhh[2]) + wih[2]*x0 + wih[3]*x1 + whh[2]*h0 + whh[3]*h1;
    float g2 = (bih[4] + bhh[4]) + wih[4]*x0 + wih[5]*x1 + whh[4]*h0 + whh[5]*h1;
    float g3 = (bih[6] + bhh[6]) + wih[6]*x0 + wih[7]*x1 + whh[6]*h0 + whh[7]*h1;
    float r0 = fsigmoid(g0);
    float r1 = fsigmoid(g1);
    float z0 = fsigmoid(g2);
    float z1 = fsigmoid(g3);
    // n gate: i_n + r * h_n  (h-part kept separate)
    float gi4 = bih[4 + 0] * 0.0f; // placeholder avoided; compute directly below
    (void)gi4;
    float in0 = bih[4]  + wih[8]*x0  + wih[9]*x1;
    float in1 = bih[5]  + wih[10]*x0 + wih[11]*x1;
    float hn0 = bhh[4]  + whh[8]*h0  + whh[9]*h1;
    float hn1 = bhh[5]  + whh[10]*h0 + whh[11]*h1;
    float n0 = ftanh(in0 + r0 * hn0);
    float n1 = ftanh(in1 + r1 * hn1);
    h0 = (1.0f - z0) * n0 + z0 * h0;
    h1 = (1.0f - z1) * n1 + z1 * h1;
}

__global__ __launch_bounds__(256) void recpolicy_kernel(
    const float* __restrict__ x,
    const float* __restrict__ w_ih_up, const float* __restrict__ w_hh_up,
    const float* __restrict__ b_ih_up, const float* __restrict__ b_hh_up,
    const float* __restrict__ w_obs,   const float* __restrict__ b_obs,
    const float* __restrict__ w_ih_dn, const float* __restrict__ w_hh_dn,
    const float* __restrict__ b_ih_dn, const float* __restrict__ b_hh_dn,
    const float* __restrict__ w_out,   const float* __restrict__ b_out,
    float* __restrict__ out, int n)
{
    const int row = blockIdx.x * blockDim.x + threadIdx.x;
    if (row >= n) return;

    // ---- uniform weight loads (wave-uniform addresses -> scalar cache) ----
    float wiu[12], whu[12], biu[6], bhu[6];
    float wid[12], whd[12], bid[6], bhd[6];
    float wobs[12], bobs[2];
    #pragma unroll
    for (int i = 0; i < 12; ++i) {
        wiu[i] = w_ih_up[i]; whu[i] = w_hh_up[i];
        wid[i] = w_ih_dn[i]; whd[i] = w_hh_dn[i];
        wobs[i] = w_obs[i];
    }
    // bih/bhh re-ordered access: gru_cell reads b[0..5] as [r0,?,r1? ...]
    // NOTE: gru_cell above indexes bih[0],bih[2],bih[4],bih[6]?? -> fix by
    // passing plain 6-element arrays and indexing 0..5 directly there.
    #pragma unroll
    for (int i = 0; i < 6; ++i) {
        biu[i] = b_ih_up[i]; bhu[i] = b_hh_up[i];
        bid[i] = b_ih_dn[i]; bhd[i] = b_hh_dn[i];
    }
    bobs[0] = b_obs[0]; bobs[1] = b_obs[1];
    const float wout0 = w_out[0], wout1 = w_out[1], bout = b_out[0];

    // ---- load x row: 18 floats = 9 aligned float2 (row stride 72 B) ----
    const float2* xr = reinterpret_cast<const float2*>(x + (size_t)row * 18);
    float xv[18];
    #pragma unroll
    for (int i = 0; i < 9; ++i) {
        float2 v = xr[i];
        xv[2 * i] = v.x;
        xv[2 * i + 1] = v.y;
    }

    // ---- up chain: i = 6..0, input (j[i], jd[i]) = (xv[4+i], xv[11+i]) ----
    float h0 = 0.0f, h1 = 0.0f;
    float hu0[7], hu1[7];
    #pragma unroll
    for (int k = 0; k < 7; ++k) {
        const int i = 6 - k;
        // gates computed inline (bias indexing 0..5):
        float g0 = (biu[0] + bhu[0]) + wiu[0]*xv[4+i] + wiu[1]*xv[11+i] + whu[0]*h0 + whu[1]*h1;
        float g1 = (biu[1] + bhu[1]) + wiu[2]*xv[4+i] + wiu[3]*xv[11+i] + whu[2]*h0 + whu[3]*h1;
        float g2 = (biu[2] + bhu[2]) + wiu[4]*xv[4+i] + wiu[5]*xv[11+i] + whu[4]*h0 + whu[5]*h1;
        float g3 = (biu[3] + bhu[3]) + wiu[6]*xv[4+i] + wiu[7]*xv[11+i] + whu[6]*h0 + whu[7]*h1;
        float r0 = fsigmoid(g0);
        float r1 = fsigmoid(g1);
        float z0 = fsigmoid(g2);
        float z1 = fsigmoid(g3);
        float in0 = biu[4] + wiu[8]*xv[4+i]  + wiu[9]*xv[11+i];
        float in1 = biu[5] + wiu[10]*xv[4+i] + wiu[11]*xv[11+i];
        float hn0 = bhu[4] + whu[8]*h0  + whu[9]*h1;
        float hn1 = bhu[5] + whu[10]*h0 + whu[11]*h1;
        float n0 = ftanh(in0 + r0 * hn0);
        float n1 = ftanh(in1 + r1 * hn1);
        h0 = (1.0f - z0) * n0 + z0 * h0;
        h1 = (1.0f - z1) * n1 + z1 * h1;
        hu0[k] = h0;
        hu1[k] = h1;
    }

    // ---- obs linear: [obs(4), h(2)] @ w_obs.T + b_obs ----
    {
        float t0 = bobs[0], t1 = bobs[1];
        t0 += wobs[0]*xv[0] + wobs[1]*xv[1] + wobs[2]*xv[2] + wobs[3]*xv[3] + wobs[4]*h0 + wobs[5]*h1;
        t1 += wobs[6]*xv[0] + wobs[7]*xv[1] + wobs[8]*xv[2] + wobs[9]*xv[3] + wobs[10]*h0 + wobs[11]*h1;
        h0 = t0;
        h1 = t1;
    }

    // ---- down chain + head ----
    float acts[7];
    #pragma unroll
    for (int k = 0; k < 7; ++k) {
        float x0 = hu0[k], x1 = hu1[k];
        float g0 = (bid[0] + bhd[0]) + wid[0]*x0 + wid[1]*x1 + whd[0]*h0 + whd[1]*h1;
        float g1 = (bid[1] + bhd[1]) + wid[2]*x0 + wid[3]*x1 + whd[2]*h0 + whd[3]*h1;
        float g2 = (bid[2] + bhd[2]) + wid[4]*x0 + wid[5]*x1 + whd[4]*h0 + whd[5]*h1;
        float g3 = (bid[3] + bhd[3]) + wid[6]*x0 + wid[7]*x1 + whd[6]*h0 + whd[7]*h1;
        float r0 = fsigmoid(g0);
        float r1 = fsigmoid(g1);
        float z0 = fsigmoid(g2);
        float z1 = fsigmoid(g3);
        float in0 = bid[4] + wid[8]*x0  + wid[9]*x1;
        float in1 = bid[5] + wid[10]*x0 + wid[11]*x1;
        float hn0 = bhd[4] + whd[8]*h0  + whd[9]*h1;
        float hn1 = bhd[5] + whd[10]*h0 + whd[11]*h1;
        float n0 = ftanh(in0 + r0 * hn0);
        float n1 = ftanh(in1 + r1 * hn1);
        h0 = (1.0f - z0) * n0 + z0 * h0;
        h1 = (1.0f - z1) * n1 + z1 * h1;
        acts[k] = wout0 * h0 + wout1 * h1 + bout;
    }

    // ---- write out row (7 f32) ----
    float* orow = out + (size_t)row * 7;
    #pragma unroll
    for (int k = 0; k < 7; ++k) orow[k] = acts[k];
}

extern "C" void kernel_launch(void* const* d_in, const int* in_sizes, int n_in,
                              void* d_out, int out_size, void* d_ws, size_t ws_size,
                              hipStream_t stream) {
    const float* x       = (const float*)d_in[0];
    const float* w_ih_up = (const float*)d_in[1];
    const float* w_hh_up = (const float*)d_in[2];
    const float* b_ih_up = (const float*)d_in[3];
    const float* b_hh_up = (const float*)d_in[4];
    const float* w_obs   = (const float*)d_in[5];
    const float* b_obs   = (const float*)d_in[6];
    const float* w_ih_dn = (const float*)d_in[7];
    const float* w_hh_dn = (const float*)d_in[8];
    const float* b_ih_dn = (const float*)d_in[9];
    const float* b_hh_dn = (const float*)d_in[10];
    const float* w_out   = (const float*)d_in[11];
    const float* b_out   = (const float*)d_in[12];
    float* out = (float*)d_out;

    const int n = in_sizes[0] / 18;
    const int block = 256;
    const int grid = (n + block - 1) / block;
    recpolicy_kernel<<<grid, block, 0, stream>>>(
        x, w_ih_up, w_hh_up, b_ih_up, b_hh_up, w_obs, b_obs,
        w_ih_dn, w_hh_dn, b_ih_dn, b_hh_dn, w_out, b_out, out, n);
}

// Round 2
// 52.939 us; speedup vs baseline: 1.3118x; 1.3118x over previous
//
#include <hip/hip_runtime.h>

// RecPolicy: per-row, 7-step bidirectional GRU (H=2) + obs linear + scalar head.
// x: (B,18) f32 = [obs(4), j(7), jd(7)] ; out: (B,7) f32
//
// R2: LDS-staged coalesced load/store, packed-f32 (v_pk_fma) cell math,
//     log2e prescaled gate weights so each activation = {exp2, add, rcp}.

using v2f = __attribute__((ext_vector_type(2))) float;

__device__ __forceinline__ float fexp2(float x) { return __builtin_amdgcn_exp2f(x); }
__device__ __forceinline__ float frcp(float x)  { return __builtin_amdgcn_rcpf(x); }

struct Cell {
    v2f wr0, wr1, ur0, ur1, br;   // r gates, prescaled by -log2(e)
    v2f wz0, wz1, uz0, uz1, bz;   // z gates, prescaled by -log2(e)
    v2f wn0, wn1, bni;            // n input part, prescaled by 2*log2(e)
    v2f un0, un1, bnh;            // n hidden part, prescaled by 2*log2(e)
};

// w_ih/w_hh are (6,2) row-major: rows 0-1 = r, 2-3 = z, 4-5 = n.
__device__ __forceinline__ Cell make_cell(const float* __restrict__ wi,
                                          const float* __restrict__ wh,
                                          const float* __restrict__ bi,
                                          const float* __restrict__ bh) {
    const float s1 = -1.4426950408889634f;  // -log2(e):  sigmoid(g)=rcp(1+exp2(s1*g))
    const float s2 =  2.8853900817779268f;  // 2*log2(e): tanh(t)=1-2*rcp(1+exp2(s2*t))
    Cell c;
    c.wr0 = (v2f){s1*wi[0], s1*wi[2]};  c.wr1 = (v2f){s1*wi[1], s1*wi[3]};
    c.ur0 = (v2f){s1*wh[0], s1*wh[2]};  c.ur1 = (v2f){s1*wh[1], s1*wh[3]};
    c.br  = (v2f){s1*(bi[0]+bh[0]), s1*(bi[1]+bh[1])};
    c.wz0 = (v2f){s1*wi[4], s1*wi[6]};  c.wz1 = (v2f){s1*wi[5], s1*wi[7]};
    c.uz0 = (v2f){s1*wh[4], s1*wh[6]};  c.uz1 = (v2f){s1*wh[5], s1*wh[7]};
    c.bz  = (v2f){s1*(bi[2]+bh[2]), s1*(bi[3]+bh[3])};
    c.wn0 = (v2f){s2*wi[8], s2*wi[10]}; c.wn1 = (v2f){s2*wi[9], s2*wi[11]};
    c.bni = (v2f){s2*bi[4], s2*bi[5]};
    c.un0 = (v2f){s2*wh[8], s2*wh[10]}; c.un1 = (v2f){s2*wh[9], s2*wh[11]};
    c.bnh = (v2f){s2*bh[4], s2*bh[5]};
    return c;
}

__device__ __forceinline__ void gru(const Cell& c, float x0, float x1, v2f& h) {
    v2f gr = c.br + c.wr0 * x0 + c.wr1 * x1 + c.ur0 * h.x + c.ur1 * h.y;
    v2f gz = c.bz + c.wz0 * x0 + c.wz1 * x1 + c.uz0 * h.x + c.uz1 * h.y;
    v2f r  = (v2f){ frcp(1.0f + fexp2(gr.x)), frcp(1.0f + fexp2(gr.y)) };
    v2f z  = (v2f){ frcp(1.0f + fexp2(gz.x)), frcp(1.0f + fexp2(gz.y)) };
    v2f in = c.bni + c.wn0 * x0 + c.wn1 * x1;
    v2f hn = c.bnh + c.un0 * h.x + c.un1 * h.y;
    v2f a  = in + r * hn;
    v2f n  = (v2f){ 1.0f - 2.0f * frcp(1.0f + fexp2(a.x)),
                    1.0f - 2.0f * frcp(1.0f + fexp2(a.y)) };
    h = n + z * (h - n);   // (1-z)*n + z*h
}

__global__ __launch_bounds__(256) void recpolicy_kernel(
    const float* __restrict__ x,
    const float* __restrict__ w_ih_up, const float* __restrict__ w_hh_up,
    const float* __restrict__ b_ih_up, const float* __restrict__ b_hh_up,
    const float* __restrict__ w_obs,   const float* __restrict__ b_obs,
    const float* __restrict__ w_ih_dn, const float* __restrict__ w_hh_dn,
    const float* __restrict__ b_ih_dn, const float* __restrict__ b_hh_dn,
    const float* __restrict__ w_out,   const float* __restrict__ b_out,
    float* __restrict__ out, int n)
{
    __shared__ float lds[4608];               // 256 rows x 18 f32 = 18 KiB
    const int tid  = threadIdx.x;
    const int row0 = blockIdx.x * 256;
    const int rows = min(256, n - row0);

    // ---- stage input block into LDS, coalesced float4 ----
    if (rows == 256) {
        const float4* src = reinterpret_cast<const float4*>(x + (size_t)row0 * 18);
        float4* dst = reinterpret_cast<float4*>(lds);
        #pragma unroll
        for (int i = 0; i < 5; ++i) {
            int idx = tid + i * 256;
            if (idx < 1152) dst[idx] = src[idx];
        }
    } else {
        for (int idx = tid; idx < rows * 18; idx += 256)
            lds[idx] = x[(size_t)row0 * 18 + idx];
    }
    __syncthreads();

    // ---- each thread pulls its row (b64 LDS reads) ----
    float xv[18];
    {
        const float2* r2 = reinterpret_cast<const float2*>(lds + tid * 18);
        #pragma unroll
        for (int i = 0; i < 9; ++i) { float2 v = r2[i]; xv[2*i] = v.x; xv[2*i+1] = v.y; }
    }
    __syncthreads();   // all input reads done before lds is reused for output

    // ---- up chain: i = 6..0, input (j[i], jd[i]) = (xv[4+i], xv[11+i]) ----
    Cell up = make_cell(w_ih_up, w_hh_up, b_ih_up, b_hh_up);
    v2f h = (v2f){0.0f, 0.0f};
    v2f hu[7];
    #pragma unroll
    for (int k = 0; k < 7; ++k) {
        const int i = 6 - k;
        gru(up, xv[4 + i], xv[11 + i], h);
        hu[k] = h;
    }

    // ---- obs linear: [obs(4), h(2)] @ w_obs.T + b_obs  (w_obs is (2,6)) ----
    {
        v2f t = (v2f){b_obs[0], b_obs[1]};
        #pragma unroll
        for (int c = 0; c < 4; ++c)
            t += (v2f){w_obs[c], w_obs[6 + c]} * xv[c];
        t += (v2f){w_obs[4], w_obs[10]} * h.x;
        t += (v2f){w_obs[5], w_obs[11]} * h.y;
        h = t;
    }

    // ---- down chain + head, acts staged into LDS ----
    Cell dn = make_cell(w_ih_dn, w_hh_dn, b_ih_dn, b_hh_dn);
    const float wo0 = w_out[0], wo1 = w_out[1], bo = b_out[0];
    #pragma unroll
    for (int k = 0; k < 7; ++k) {
        gru(dn, hu[k].x, hu[k].y, h);
        lds[tid * 7 + k] = wo0 * h.x + wo1 * h.y + bo;
    }
    __syncthreads();

    // ---- coalesced float4 store of the block's 256x7 outputs ----
    if (rows == 256) {
        float4* dst = reinterpret_cast<float4*>(out + (size_t)row0 * 7);
        const float4* src = reinterpret_cast<const float4*>(lds);
        #pragma unroll
        for (int i = 0; i < 2; ++i) {
            int idx = tid + i * 256;
            if (idx < 448) dst[idx] = src[idx];
        }
    } else {
        for (int idx = tid; idx < rows * 7; idx += 256)
            out[(size_t)row0 * 7 + idx] = lds[idx];
    }
}

extern "C" void kernel_launch(void* const* d_in, const int* in_sizes, int n_in,
                              void* d_out, int out_size, void* d_ws, size_t ws_size,
                              hipStream_t stream) {
    const float* x       = (const float*)d_in[0];
    const float* w_ih_up = (const float*)d_in[1];
    const float* w_hh_up = (const float*)d_in[2];
    const float* b_ih_up = (const float*)d_in[3];
    const float* b_hh_up = (const float*)d_in[4];
    const float* w_obs   = (const float*)d_in[5];
    const float* b_obs   = (const float*)d_in[6];
    const float* w_ih_dn = (const float*)d_in[7];
    const float* w_hh_dn = (const float*)d_in[8];
    const float* b_ih_dn = (const float*)d_in[9];
    const float* b_hh_dn = (const float*)d_in[10];
    const float* w_out   = (const float*)d_in[11];
    const float* b_out   = (const float*)d_in[12];
    float* out = (float*)d_out;

    const int n = in_sizes[0] / 18;
    const int block = 256;
    const int grid = (n + block - 1) / block;
    recpolicy_kernel<<<grid, block, 0, stream>>>(
        x, w_ih_up, w_hh_up, b_ih_up, b_hh_up, w_obs, b_obs,
        w_ih_dn, w_hh_dn, b_ih_dn, b_hh_dn, w_out, b_out, out, n);
}